// Round 4
// baseline (69380.359 us; speedup 1.0000x reference)
//
#include <hip/hip_runtime.h>
#include <hip/hip_bf16.h>
#include <stdint.h>

#define NB    256
#define LSEQ  1024
#define CINC  16
#define SSTEP 128
#define HDIM  256
#define NLAY  6
#define H3    768

__device__ __forceinline__ float sigm(float x){ return 1.f/(1.f+__expf(-x)); }
__device__ __forceinline__ float tanh_(float x){ float e=__expf(2.f*x); return 1.f - 2.f/(e+1.f); }

// dot( f32 LDS vector , f32 global row ), n multiple of 4
__device__ __forceinline__ float dotv(const float* __restrict__ a,
                                      const float* __restrict__ w, int n)
{
    float acc = 0.f;
    const float4* wp = (const float4*)w;
    const float4* ap = (const float4*)a;
    #pragma unroll 8
    for (int i = 0; i < (n >> 2); ++i) {
        float4 W = wp[i];
        float4 A = ap[i];
        acc += A.x*W.x + A.y*W.y + A.z*W.z + A.w*W.w;
    }
    return acc;
}

__global__ __launch_bounds__(256)
void encoder_kernel(const float* __restrict__ x,
                    const float* __restrict__ Wih0, const float* __restrict__ WihR,
                    const float* __restrict__ Whh,  const float* __restrict__ bih,
                    const float* __restrict__ bhh,  const float* __restrict__ h0,
                    const float* __restrict__ aW1,  const float* __restrict__ aW2,
                    const float* __restrict__ aW3,  const float* __restrict__ aW4,
                    float* __restrict__ enc)
{
    const int b = blockIdx.x;
    const int j = threadIdx.x;

    __shared__ __align__(16) float h[NLAY][HDIM];
    __shared__ __align__(16) float inp[HDIM];
    __shared__ __align__(16) float hnew[HDIM];
    __shared__ __align__(16) float hs[HDIM];
    __shared__ __align__(16) float a1[2*HDIM];
    __shared__ __align__(16) float a2[2*HDIM];
    __shared__ __align__(16) float a3[2*HDIM];

    #pragma unroll
    for (int l = 0; l < NLAY; ++l) h[l][j] = h0[l*HDIM + j];

    for (int t = 0; t < SSTEP; ++t) {
        // xt = x[b, t*8:(t+1)*8, :] flattened -> 128 contiguous floats
        if (j < 128) inp[j] = x[(size_t)b*(LSEQ*CINC) + (size_t)t*128 + j];
        __syncthreads();

        for (int l = 0; l < NLAY; ++l) {
            const int in_dim = l ? HDIM : 128;
            const float* wih = l ? (WihR + (size_t)(l-1)*H3*HDIM) : Wih0;
            const float* whh = Whh + (size_t)l*H3*HDIM;

            // ---- GRU cell: thread j owns feature j (gate rows j, j+256, j+512)
            float gr = bih[l*H3 + j]        + bhh[l*H3 + j];
            float gz = bih[l*H3 + HDIM + j] + bhh[l*H3 + HDIM + j];
            float gi = bih[l*H3 + 2*HDIM + j];   // i_n (kept separate!)
            float gh = bhh[l*H3 + 2*HDIM + j];   // h_n

            gr += dotv(inp,  wih + (size_t)j*in_dim,            in_dim);
            gz += dotv(inp,  wih + (size_t)(j+HDIM)*in_dim,     in_dim);
            gi += dotv(inp,  wih + (size_t)(j+2*HDIM)*in_dim,   in_dim);
            gr += dotv(h[l], whh + (size_t)j*HDIM,              HDIM);
            gz += dotv(h[l], whh + (size_t)(j+HDIM)*HDIM,       HDIM);
            gh += dotv(h[l], whh + (size_t)(j+2*HDIM)*HDIM,     HDIM);

            float r = sigm(gr), z = sigm(gz);
            float n = tanh_(gi + r*gh);
            float hv = (1.f - z)*n + z*h[l][j];
            hnew[j] = hv;
            __syncthreads();

            // ---- ascending sort via rank (ties broken by index -> permutation)
            {
                int rank = 0;
                const float4* hp = (const float4*)hnew;
                #pragma unroll 8
                for (int k4 = 0; k4 < HDIM/4; ++k4) {
                    float4 u = hp[k4];
                    int k = 4*k4;
                    rank += (u.x < hv) || (u.x == hv && (k+0) < j);
                    rank += (u.y < hv) || (u.y == hv && (k+1) < j);
                    rank += (u.z < hv) || (u.z == hv && (k+2) < j);
                    rank += (u.w < hv) || (u.w == hv && (k+3) < j);
                }
                hs[rank] = hv;
            }
            __syncthreads();

            // ---- a1 = se @ W1^T ; se rows = (h, sorted(h)); flat [2*256]
            {
                const float4* wp = (const float4*)(aW1 + (size_t)l*HDIM*HDIM + (size_t)j*HDIM);
                const float4* hp = (const float4*)hnew;
                const float4* sp = (const float4*)hs;
                float acc0 = 0.f, acc1 = 0.f;
                #pragma unroll 8
                for (int i = 0; i < HDIM/4; ++i) {
                    float4 W = wp[i];
                    float4 P = hp[i];
                    float4 Q = sp[i];
                    acc0 += P.x*W.x + P.y*W.y + P.z*W.z + P.w*W.w;
                    acc1 += Q.x*W.x + Q.y*W.y + Q.z*W.z + Q.w*W.w;
                }
                a1[j] = acc0;
                a1[HDIM + j] = acc1;
            }
            __syncthreads();

            // ---- a2 = shuffle(a1 as [4][128]) @ W2^T
            // shuf[g][kk] = a1[(kk&3)*128 + g*32 + kk/4]
            #pragma unroll
            for (int rep = 0; rep < 2; ++rep) {
                int o = j + rep*256;
                int g = o >> 7, m = o & 127;
                const float* w2r = aW2 + (size_t)l*128*128 + (size_t)m*128;
                float acc = 0.f;
                #pragma unroll 8
                for (int kk = 0; kk < 128; kk += 4) {
                    float4 W = *(const float4*)(w2r + kk);
                    int base = (g << 5) + (kk >> 2);
                    acc += a1[base      ]*W.x + a1[base + 128]*W.y
                         + a1[base + 256]*W.z + a1[base + 384]*W.w;
                }
                a2[o] = acc;
            }
            __syncthreads();

            // ---- a3 = relu( shuffle(a2) @ W3^T )
            #pragma unroll
            for (int rep = 0; rep < 2; ++rep) {
                int o = j + rep*256;
                int g = o >> 7, m = o & 127;
                const float* w3r = aW3 + (size_t)l*128*128 + (size_t)m*128;
                float acc = 0.f;
                #pragma unroll 8
                for (int kk = 0; kk < 128; kk += 4) {
                    float4 W = *(const float4*)(w3r + kk);
                    int base = (g << 5) + (kk >> 2);
                    acc += a2[base      ]*W.x + a2[base + 128]*W.y
                         + a2[base + 256]*W.z + a2[base + 384]*W.w;
                }
                a3[o] = fmaxf(acc, 0.f);
            }
            __syncthreads();

            // ---- a4 = a3(flat 512) @ W4^T ; h_out = hnew * sigmoid(a4)
            {
                float acc = dotv(a3, aW4 + (size_t)l*HDIM*2*HDIM + (size_t)j*2*HDIM, 2*HDIM);
                float ho = hnew[j] * sigm(acc);
                h[l][j] = ho;
                inp[j]  = ho;
                if (l == NLAY-1)
                    enc[((size_t)b*SSTEP + t)*HDIM + j] = ho;
            }
            __syncthreads();
        }
    }
}

// ---------------- decoders ----------------

__global__ __launch_bounds__(256)
void seqdec_kernel(const float* __restrict__ enc,
                   const float* __restrict__ W1, const float* __restrict__ b1,
                   const float* __restrict__ W2, const float* __restrict__ b2,
                   const float* __restrict__ W3, const float* __restrict__ b3,
                   const float* __restrict__ W4, const float* __restrict__ b4,
                   float* __restrict__ yseq)
{
    int idx = blockIdx.x*blockDim.x + threadIdx.x;
    if (idx >= NB*SSTEP) return;
    int b = idx >> 7, s = idx & 127;
    const float* e = enc + (size_t)idx*HDIM;

    float A[8][4], Bm[8][4], Cm[8][4];
    #pragma unroll
    for (int g = 0; g < 8; ++g)
      #pragma unroll
      for (int o = 0; o < 4; ++o) {
        float acc = b1[o];
        for (int k = 0; k < 32; ++k) acc += e[g*32+k] * W1[o*32+k];
        A[g][o] = acc;
      }
    #pragma unroll
    for (int r = 0; r < 8; ++r)
      #pragma unroll
      for (int c = 0; c < 4; ++c) {
        float acc = b2[c];
        #pragma unroll
        for (int q = 0; q < 4; ++q)
            acc += A[(4*r+q)&7][(4*r+q)>>3] * W2[c*4+q];
        Bm[r][c] = acc;
      }
    #pragma unroll
    for (int r = 0; r < 8; ++r)
      #pragma unroll
      for (int c = 0; c < 4; ++c) {
        float acc = b3[c];
        #pragma unroll
        for (int q = 0; q < 4; ++q)
            acc += Bm[(4*r+q)&7][(4*r+q)>>3] * W3[c*4+q];
        Cm[r][c] = acc;
      }
    // z[o][g] = Cflat[o*8+g], Cflat[m] = Cm[m/4][m%4]; y4[o][w] = z[o]·W4[w] + b4[w]
    #pragma unroll
    for (int o = 0; o < 4; ++o)
      #pragma unroll
      for (int w = 0; w < 8; ++w) {
        float acc = b4[w];
        #pragma unroll
        for (int g = 0; g < 8; ++g)
            acc += Cm[(o*8+g)>>2][(o*8+g)&3] * W4[w*8+g];
        yseq[((size_t)b*LSEQ + s*8 + w)*4 + o] = acc;
      }
}

__global__ __launch_bounds__(64)
void onedec_kernel(const float* __restrict__ enc,
                   const float* __restrict__ W1, const float* __restrict__ b1,
                   const float* __restrict__ W2, const float* __restrict__ b2,
                   const float* __restrict__ W3, const float* __restrict__ b3,
                   const float* __restrict__ W4, const float* __restrict__ b4,
                   float* __restrict__ yone)
{
    int b = blockIdx.x;
    int tid = threadIdx.x;
    __shared__ float part[10][4];
    if (tid < 10) {
        int s = SSTEP - 10 + tid;
        const float* e = enc + ((size_t)b*SSTEP + s)*HDIM;
        float A[8][4], Bm[8][4], Cm[8][4];
        #pragma unroll
        for (int g = 0; g < 8; ++g)
          #pragma unroll
          for (int o = 0; o < 4; ++o) {
            float acc = b1[o];
            for (int k = 0; k < 32; ++k) acc += e[g*32+k] * W1[o*32+k];
            A[g][o] = acc;
          }
        #pragma unroll
        for (int r = 0; r < 8; ++r)
          #pragma unroll
          for (int c = 0; c < 4; ++c) {
            float acc = b2[c];
            #pragma unroll
            for (int q = 0; q < 4; ++q)
                acc += A[(4*r+q)&7][(4*r+q)>>3] * W2[c*4+q];
            Bm[r][c] = acc;
          }
        #pragma unroll
        for (int r = 0; r < 8; ++r)
          #pragma unroll
          for (int c = 0; c < 4; ++c) {
            float acc = b3[c];
            #pragma unroll
            for (int q = 0; q < 4; ++q)
                acc += Bm[(4*r+q)&7][(4*r+q)>>3] * W3[c*4+q];
            Cm[r][c] = fmaxf(acc, 0.f);   // relu
          }
        #pragma unroll
        for (int jj = 0; jj < 4; ++jj) {
            float acc = b4[jj];
            #pragma unroll
            for (int m = 0; m < 32; ++m)
                acc += Cm[m>>2][m&3] * W4[jj*32+m];
            part[tid][jj] = sigm(acc);
        }
    }
    __syncthreads();
    if (tid < 4) {
        float acc = 0.f;
        #pragma unroll
        for (int k = 0; k < 10; ++k) acc += part[k][tid];
        yone[b*4 + tid] = acc * 0.1f;
    }
}

extern "C" void kernel_launch(void* const* d_in, const int* in_sizes, int n_in,
                              void* d_out, int out_size, void* d_ws, size_t ws_size,
                              hipStream_t stream)
{
    const float* x    = (const float*)d_in[0];
    const float* Wih0 = (const float*)d_in[1];
    const float* WihR = (const float*)d_in[2];
    const float* Whh  = (const float*)d_in[3];
    const float* bih  = (const float*)d_in[4];
    const float* bhh  = (const float*)d_in[5];
    const float* h0   = (const float*)d_in[6];
    const float* aW1  = (const float*)d_in[7];
    const float* aW2  = (const float*)d_in[8];
    const float* aW3  = (const float*)d_in[9];
    const float* aW4  = (const float*)d_in[10];
    const float* sdW1 = (const float*)d_in[11];
    const float* sdb1 = (const float*)d_in[12];
    const float* sdW2 = (const float*)d_in[13];
    const float* sdb2 = (const float*)d_in[14];
    const float* sdW3 = (const float*)d_in[15];
    const float* sdb3 = (const float*)d_in[16];
    const float* sdW4 = (const float*)d_in[17];
    const float* sdb4 = (const float*)d_in[18];
    const float* odW1 = (const float*)d_in[19];
    const float* odb1 = (const float*)d_in[20];
    const float* odW2 = (const float*)d_in[21];
    const float* odb2 = (const float*)d_in[22];
    const float* odW3 = (const float*)d_in[23];
    const float* odb3 = (const float*)d_in[24];
    const float* odW4 = (const float*)d_in[25];
    const float* odb4 = (const float*)d_in[26];

    float* out  = (float*)d_out;
    float* enc  = out;                                   // [256][128][256]
    float* yseq = out + (size_t)NB*SSTEP*HDIM;           // [256][1024][4]
    float* yone = yseq + (size_t)NB*LSEQ*4;              // [256][4]

    hipLaunchKernelGGL(encoder_kernel, dim3(NB), dim3(HDIM), 0, stream,
                       x, Wih0, WihR, Whh, bih, bhh, h0, aW1, aW2, aW3, aW4, enc);
    hipLaunchKernelGGL(seqdec_kernel, dim3((NB*SSTEP)/256), dim3(256), 0, stream,
                       enc, sdW1, sdb1, sdW2, sdb2, sdW3, sdb3, sdW4, sdb4, yseq);
    hipLaunchKernelGGL(onedec_kernel, dim3(NB), dim3(64), 0, stream,
                       enc, odW1, odb1, odW2, odb2, odW3, odb3, odW4, odb4, yone);
}

// Round 5
// 67860.907 us; speedup vs baseline: 1.0224x; 1.0224x over previous
//
#include <hip/hip_runtime.h>
#include <hip/hip_bf16.h>
#include <stdint.h>

#define NB    256
#define LSEQ  1024
#define CINC  16
#define SSTEP 128
#define HDIM  256
#define NLAY  6
#define H3    768

__device__ __forceinline__ float sigm(float x){ return 1.f/(1.f+__expf(-x)); }
__device__ __forceinline__ float tanh_(float x){ float e=__expf(2.f*x); return 1.f - 2.f/(e+1.f); }

template<int N4>
__device__ __forceinline__ float dotk(const float* __restrict__ a,
                                      const float* __restrict__ w)
{
    const float4* ap = (const float4*)a;
    const float4* wp = (const float4*)w;
    float acc = 0.f;
    #pragma unroll
    for (int i = 0; i < N4; ++i) {
        float4 A = ap[i], W = wp[i];
        acc += A.x*W.x + A.y*W.y + A.z*W.z + A.w*W.w;
    }
    return acc;
}

// 1024 threads: thread = (j, p), j = feature 0..255, p = K-quarter 0..3.
// All GEMV K-dims split 4-way (or 2-way for a2/a3), partials combined via LDS.
__global__ __launch_bounds__(1024)
void encoder_kernel(const float* __restrict__ x,
                    const float* __restrict__ Wih0, const float* __restrict__ WihR,
                    const float* __restrict__ Whh,  const float* __restrict__ bih,
                    const float* __restrict__ bhh,  const float* __restrict__ h0,
                    const float* __restrict__ aW1,  const float* __restrict__ aW2,
                    const float* __restrict__ aW3,  const float* __restrict__ aW4,
                    float* __restrict__ enc)
{
    const int b   = blockIdx.x;
    const int tid = threadIdx.x;
    const int j   = tid & 255;
    const int p   = tid >> 8;          // 0..3

    __shared__ __align__(16) float h[NLAY][HDIM];
    __shared__ __align__(16) float inp[HDIM];
    __shared__ __align__(16) float hnew[HDIM];
    __shared__ __align__(16) float hs[HDIM];
    __shared__ __align__(16) float a1[2*HDIM];
    __shared__ __align__(16) float a2v[2*HDIM];
    __shared__ __align__(16) float a3v[2*HDIM];
    __shared__ __align__(16) float part[4096];   // 16 KB partial-sum buffer

    for (int idx = tid; idx < NLAY*HDIM; idx += 1024)
        h[idx >> 8][idx & 255] = h0[idx];

    for (int t = 0; t < SSTEP; ++t) {
        if (tid < 128) inp[tid] = x[(size_t)b*(LSEQ*CINC) + (size_t)t*128 + tid];
        __syncthreads();   // also covers h init at t=0

        for (int l = 0; l < NLAY; ++l) {
            const float* whh = Whh + (size_t)l*H3*HDIM;
            const float* hl  = h[l];

            // ---- GRU partials: thread (j,p) does K-quarter of all 6 dots
            {
                float pr, pz, pi;
                if (l == 0) {
                    const float* ip = inp + (p << 5);
                    pr = dotk<8>(ip, Wih0 + (size_t)(j      )*128 + (p << 5));
                    pz = dotk<8>(ip, Wih0 + (size_t)(j + 256)*128 + (p << 5));
                    pi = dotk<8>(ip, Wih0 + (size_t)(j + 512)*128 + (p << 5));
                } else {
                    const float* wr = WihR + (size_t)(l-1)*H3*HDIM;
                    const float* ip = inp + (p << 6);
                    pr = dotk<16>(ip, wr + (size_t)(j      )*256 + (p << 6));
                    pz = dotk<16>(ip, wr + (size_t)(j + 256)*256 + (p << 6));
                    pi = dotk<16>(ip, wr + (size_t)(j + 512)*256 + (p << 6));
                }
                const float* hp = hl + (p << 6);
                pr += dotk<16>(hp, whh + (size_t)(j      )*256 + (p << 6));
                pz += dotk<16>(hp, whh + (size_t)(j + 256)*256 + (p << 6));
                float ph_ = dotk<16>(hp, whh + (size_t)(j + 512)*256 + (p << 6));
                part[        (p << 8) + j] = pr;
                part[1024 + (p << 8) + j] = pz;
                part[2048 + (p << 8) + j] = pi;   // i_n input-side
                part[3072 + (p << 8) + j] = ph_;  // h_n hidden-side (kept separate)
            }
            __syncthreads();

            if (tid < 256) {
                float gr = bih[l*H3 + tid] + bhh[l*H3 + tid]
                         + part[tid] + part[256+tid] + part[512+tid] + part[768+tid];
                float gz = bih[l*H3 + 256 + tid] + bhh[l*H3 + 256 + tid]
                         + part[1024+tid] + part[1280+tid] + part[1536+tid] + part[1792+tid];
                float gi = bih[l*H3 + 512 + tid]
                         + part[2048+tid] + part[2304+tid] + part[2560+tid] + part[2816+tid];
                float gh = bhh[l*H3 + 512 + tid]
                         + part[3072+tid] + part[3328+tid] + part[3584+tid] + part[3840+tid];
                float r = sigm(gr), z = sigm(gz);
                float n = tanh_(gi + r*gh);
                hnew[tid] = (1.f - z)*n + z*hl[tid];
            }
            __syncthreads();

            // ---- rank-sort partial: quarter of the compare range per thread
            {
                float hv = hnew[j];
                int cnt = 0;
                const float4* hp4 = (const float4*)(hnew + (p << 6));
                #pragma unroll
                for (int i = 0; i < 16; ++i) {
                    float4 u = hp4[i];
                    int k = (p << 6) + 4*i;
                    cnt += (u.x < hv) || (u.x == hv && (k  ) < j);
                    cnt += (u.y < hv) || (u.y == hv && (k+1) < j);
                    cnt += (u.z < hv) || (u.z == hv && (k+2) < j);
                    cnt += (u.w < hv) || (u.w == hv && (k+3) < j);
                }
                ((int*)part)[(p << 8) + j] = cnt;
            }
            __syncthreads();
            if (tid < 256) {
                const int* ip_ = (const int*)part;
                int rank = ip_[tid] + ip_[256+tid] + ip_[512+tid] + ip_[768+tid];
                hs[rank] = hnew[tid];
            }
            __syncthreads();

            // ---- a1 = se @ W1^T : (j,p) does quarter-K of both rows, reusing W
            {
                const float4* w4  = (const float4*)(aW1 + (size_t)l*65536 + (size_t)j*256 + (p << 6));
                const float4* hp4 = (const float4*)(hnew + (p << 6));
                const float4* sp4 = (const float4*)(hs   + (p << 6));
                float acc0 = 0.f, acc1 = 0.f;
                #pragma unroll
                for (int i = 0; i < 16; ++i) {
                    float4 W = w4[i], P = hp4[i], Q = sp4[i];
                    acc0 += P.x*W.x + P.y*W.y + P.z*W.z + P.w*W.w;
                    acc1 += Q.x*W.x + Q.y*W.y + Q.z*W.z + Q.w*W.w;
                }
                part[        (p << 8) + j] = acc0;
                part[1024 + (p << 8) + j] = acc1;
            }
            __syncthreads();
            if (tid < 512) {
                int e = tid >> 8, jj = tid & 255, base = e << 10;
                a1[tid] = part[base+jj] + part[base+256+jj] + part[base+512+jj] + part[base+768+jj];
            }
            __syncthreads();

            // ---- a2 = shuffle(a1 as [4][128]) @ W2^T : 2 threads/output, half-K each
            {
                int o = tid >> 1, half = tid & 1;
                int g = o >> 7, m = o & 127;
                const float4* w4 = (const float4*)(aW2 + (size_t)l*16384 + (size_t)m*128);
                float acc = 0.f;
                #pragma unroll
                for (int u = 0; u < 16; ++u) {
                    int i = (half << 4) + u;
                    float4 W = w4[i];
                    int base = (g << 5) + i;
                    acc += a1[base]*W.x + a1[base+128]*W.y + a1[base+256]*W.z + a1[base+384]*W.w;
                }
                part[(half << 9) + o] = acc;
            }
            __syncthreads();
            if (tid < 512) a2v[tid] = part[tid] + part[512 + tid];
            __syncthreads();

            // ---- a3 = relu( shuffle(a2) @ W3^T )
            {
                int o = tid >> 1, half = tid & 1;
                int g = o >> 7, m = o & 127;
                const float4* w4 = (const float4*)(aW3 + (size_t)l*16384 + (size_t)m*128);
                float acc = 0.f;
                #pragma unroll
                for (int u = 0; u < 16; ++u) {
                    int i = (half << 4) + u;
                    float4 W = w4[i];
                    int base = (g << 5) + i;
                    acc += a2v[base]*W.x + a2v[base+128]*W.y + a2v[base+256]*W.z + a2v[base+384]*W.w;
                }
                part[(half << 9) + o] = acc;
            }
            __syncthreads();
            if (tid < 512) a3v[tid] = fmaxf(part[tid] + part[512 + tid], 0.f);
            __syncthreads();

            // ---- a4 = a3 @ W4^T ; epilogue
            part[(p << 8) + j] = dotk<32>(a3v + (p << 7),
                                          aW4 + (size_t)l*131072 + (size_t)j*512 + (p << 7));
            __syncthreads();
            if (tid < 256) {
                float acc = part[tid] + part[256+tid] + part[512+tid] + part[768+tid];
                float ho = hnew[tid] * sigm(acc);
                h[l][tid] = ho;
                inp[tid]  = ho;
                if (l == NLAY-1)
                    enc[((size_t)b*SSTEP + t)*HDIM + tid] = ho;
            }
            __syncthreads();
        }
    }
}

// ---------------- decoders (unchanged, negligible cost) ----------------

__global__ __launch_bounds__(256)
void seqdec_kernel(const float* __restrict__ enc,
                   const float* __restrict__ W1, const float* __restrict__ b1,
                   const float* __restrict__ W2, const float* __restrict__ b2,
                   const float* __restrict__ W3, const float* __restrict__ b3,
                   const float* __restrict__ W4, const float* __restrict__ b4,
                   float* __restrict__ yseq)
{
    int idx = blockIdx.x*blockDim.x + threadIdx.x;
    if (idx >= NB*SSTEP) return;
    int b = idx >> 7, s = idx & 127;
    const float* e = enc + (size_t)idx*HDIM;

    float A[8][4], Bm[8][4], Cm[8][4];
    #pragma unroll
    for (int g = 0; g < 8; ++g)
      #pragma unroll
      for (int o = 0; o < 4; ++o) {
        float acc = b1[o];
        for (int k = 0; k < 32; ++k) acc += e[g*32+k] * W1[o*32+k];
        A[g][o] = acc;
      }
    #pragma unroll
    for (int r = 0; r < 8; ++r)
      #pragma unroll
      for (int c = 0; c < 4; ++c) {
        float acc = b2[c];
        #pragma unroll
        for (int q = 0; q < 4; ++q)
            acc += A[(4*r+q)&7][(4*r+q)>>3] * W2[c*4+q];
        Bm[r][c] = acc;
      }
    #pragma unroll
    for (int r = 0; r < 8; ++r)
      #pragma unroll
      for (int c = 0; c < 4; ++c) {
        float acc = b3[c];
        #pragma unroll
        for (int q = 0; q < 4; ++q)
            acc += Bm[(4*r+q)&7][(4*r+q)>>3] * W3[c*4+q];
        Cm[r][c] = acc;
      }
    #pragma unroll
    for (int o = 0; o < 4; ++o)
      #pragma unroll
      for (int w = 0; w < 8; ++w) {
        float acc = b4[w];
        #pragma unroll
        for (int g = 0; g < 8; ++g)
            acc += Cm[(o*8+g)>>2][(o*8+g)&3] * W4[w*8+g];
        yseq[((size_t)b*LSEQ + s*8 + w)*4 + o] = acc;
      }
}

__global__ __launch_bounds__(64)
void onedec_kernel(const float* __restrict__ enc,
                   const float* __restrict__ W1, const float* __restrict__ b1,
                   const float* __restrict__ W2, const float* __restrict__ b2,
                   const float* __restrict__ W3, const float* __restrict__ b3,
                   const float* __restrict__ W4, const float* __restrict__ b4,
                   float* __restrict__ yone)
{
    int b = blockIdx.x;
    int tid = threadIdx.x;
    __shared__ float part[10][4];
    if (tid < 10) {
        int s = SSTEP - 10 + tid;
        const float* e = enc + ((size_t)b*SSTEP + s)*HDIM;
        float A[8][4], Bm[8][4], Cm[8][4];
        #pragma unroll
        for (int g = 0; g < 8; ++g)
          #pragma unroll
          for (int o = 0; o < 4; ++o) {
            float acc = b1[o];
            for (int k = 0; k < 32; ++k) acc += e[g*32+k] * W1[o*32+k];
            A[g][o] = acc;
          }
        #pragma unroll
        for (int r = 0; r < 8; ++r)
          #pragma unroll
          for (int c = 0; c < 4; ++c) {
            float acc = b2[c];
            #pragma unroll
            for (int q = 0; q < 4; ++q)
                acc += A[(4*r+q)&7][(4*r+q)>>3] * W2[c*4+q];
            Bm[r][c] = acc;
          }
        #pragma unroll
        for (int r = 0; r < 8; ++r)
          #pragma unroll
          for (int c = 0; c < 4; ++c) {
            float acc = b3[c];
            #pragma unroll
            for (int q = 0; q < 4; ++q)
                acc += Bm[(4*r+q)&7][(4*r+q)>>3] * W3[c*4+q];
            Cm[r][c] = fmaxf(acc, 0.f);   // relu
          }
        #pragma unroll
        for (int jj = 0; jj < 4; ++jj) {
            float acc = b4[jj];
            #pragma unroll
            for (int m = 0; m < 32; ++m)
                acc += Cm[m>>2][m&3] * W4[jj*32+m];
            part[tid][jj] = sigm(acc);
        }
    }
    __syncthreads();
    if (tid < 4) {
        float acc = 0.f;
        #pragma unroll
        for (int k = 0; k < 10; ++k) acc += part[k][tid];
        yone[b*4 + tid] = acc * 0.1f;
    }
}

extern "C" void kernel_launch(void* const* d_in, const int* in_sizes, int n_in,
                              void* d_out, int out_size, void* d_ws, size_t ws_size,
                              hipStream_t stream)
{
    const float* x    = (const float*)d_in[0];
    const float* Wih0 = (const float*)d_in[1];
    const float* WihR = (const float*)d_in[2];
    const float* Whh  = (const float*)d_in[3];
    const float* bih  = (const float*)d_in[4];
    const float* bhh  = (const float*)d_in[5];
    const float* h0   = (const float*)d_in[6];
    const float* aW1  = (const float*)d_in[7];
    const float* aW2  = (const float*)d_in[8];
    const float* aW3  = (const float*)d_in[9];
    const float* aW4  = (const float*)d_in[10];
    const float* sdW1 = (const float*)d_in[11];
    const float* sdb1 = (const float*)d_in[12];
    const float* sdW2 = (const float*)d_in[13];
    const float* sdb2 = (const float*)d_in[14];
    const float* sdW3 = (const float*)d_in[15];
    const float* sdb3 = (const float*)d_in[16];
    const float* sdW4 = (const float*)d_in[17];
    const float* sdb4 = (const float*)d_in[18];
    const float* odW1 = (const float*)d_in[19];
    const float* odb1 = (const float*)d_in[20];
    const float* odW2 = (const float*)d_in[21];
    const float* odb2 = (const float*)d_in[22];
    const float* odW3 = (const float*)d_in[23];
    const float* odb3 = (const float*)d_in[24];
    const float* odW4 = (const float*)d_in[25];
    const float* odb4 = (const float*)d_in[26];

    float* out  = (float*)d_out;
    float* enc  = out;                                   // [256][128][256]
    float* yseq = out + (size_t)NB*SSTEP*HDIM;           // [256][1024][4]
    float* yone = yseq + (size_t)NB*LSEQ*4;              // [256][4]

    hipLaunchKernelGGL(encoder_kernel, dim3(NB), dim3(1024), 0, stream,
                       x, Wih0, WihR, Whh, bih, bhh, h0, aW1, aW2, aW3, aW4, enc);
    hipLaunchKernelGGL(seqdec_kernel, dim3((NB*SSTEP)/256), dim3(256), 0, stream,
                       enc, sdW1, sdb1, sdW2, sdb2, sdW3, sdb3, sdW4, sdb4, yseq);
    hipLaunchKernelGGL(onedec_kernel, dim3(NB), dim3(64), 0, stream,
                       enc, odW1, odb1, odW2, odb2, odW3, odb3, odW4, odb4, yone);
}